// Round 3
// baseline (2279.309 us; speedup 1.0000x reference)
//
#include <hip/hip_runtime.h>
#include <hip/hip_bf16.h>

#define NN 30000          // N_SPOT == N_USER
#define ATT_IN 512
#define HID 256

// ---------------- degree count ----------------
__global__ __launch_bounds__(256) void k_count_deg(
    const int* __restrict__ us, const int* __restrict__ su, int E,
    int* __restrict__ d_us_s, int* __restrict__ d_us_d,
    int* __restrict__ d_su_s, int* __restrict__ d_su_d) {
  int e = blockIdx.x * 256 + threadIdx.x;
  if (e < E) {
    atomicAdd(&d_us_s[us[e]], 1);
    atomicAdd(&d_us_d[us[E + e]], 1);
    atomicAdd(&d_su_s[su[e]], 1);
    atomicAdd(&d_su_d[su[E + e]], 1);
  }
}

// ---------------- exclusive scan of n ints (single block) ----------------
__global__ __launch_bounds__(1024) void k_scan(
    const int* __restrict__ deg, int* __restrict__ rp, int n) {
  __shared__ int sums[1024];
  int t = threadIdx.x;
  int chunk = (n + 1023) / 1024;
  int lo = t * chunk, hi = lo + chunk;
  if (hi > n) hi = n;
  if (lo > n) lo = n;
  int s = 0;
  for (int i = lo; i < hi; ++i) s += deg[i];
  sums[t] = s;
  __syncthreads();
  for (int off = 1; off < 1024; off <<= 1) {
    int v = (t >= off) ? sums[t - off] : 0;
    __syncthreads();
    sums[t] += v;
    __syncthreads();
  }
  int run = sums[t] - s;  // exclusive prefix of my chunk
  for (int i = lo; i < hi; ++i) { rp[i] = run; run += deg[i]; }
  if (t == 1023) rp[n] = sums[1023];
}

// ---------------- CSR fill (by destination) ----------------
__global__ __launch_bounds__(256) void k_fill_csr(
    const int* __restrict__ src, const int* __restrict__ dst,
    const int* __restrict__ deg_s, const int* __restrict__ deg_d,
    const int* __restrict__ rp, int* __restrict__ fill,
    int* __restrict__ col, float* __restrict__ wv, int E) {
  int e = blockIdx.x * 256 + threadIdx.x;
  if (e < E) {
    int s = src[e], d = dst[e];
    int pos = rp[d] + atomicAdd(&fill[d], 1);
    col[pos] = s;
    wv[pos] = 1.0f / sqrtf((float)deg_s[s] * (float)deg_d[d]);
  }
}

// ---------------- wq[h][i] = sum_p W_att[h][i][p] * q[h][p] ----------------
__global__ __launch_bounds__(256) void k_wq(
    const float* __restrict__ W_att, const float* __restrict__ q_att,
    float* __restrict__ wq) {
  int g = blockIdx.x * 256 + threadIdx.x;
  if (g < 4 * ATT_IN) {
    int h = g >> 9, i = g & 511;
    const float* w = W_att + (size_t)h * ATT_IN * 128 + (size_t)i * 128;
    const float* q = q_att + h * 128;
    float s = 0.f;
    for (int p = 0; p < 128; ++p) s += w[p] * q[p];
    wq[g] = s;
  }
}

// ---------------- per-node attention weights (softmax over S=5) ----------------
// att[n][h][s], one wave per node
__global__ __launch_bounds__(256) void k_att(
    const float* __restrict__ x_spot, const float* __restrict__ wq,
    float* __restrict__ att) {
  int wave = threadIdx.x >> 6, lane = threadIdx.x & 63;
  int n = blockIdx.x * 4 + wave;
  // load wq fragment for my lane: wreg[h][0..7]
  float wreg[4][8];
  for (int h = 0; h < 4; ++h) {
    const float4* p = (const float4*)(wq + h * ATT_IN + lane * 8);
    float4 a = p[0], b = p[1];
    wreg[h][0] = a.x; wreg[h][1] = a.y; wreg[h][2] = a.z; wreg[h][3] = a.w;
    wreg[h][4] = b.x; wreg[h][5] = b.y; wreg[h][6] = b.z; wreg[h][7] = b.w;
  }
  float part[5][4];
  const float* xrow = x_spot + (size_t)n * (5 * ATT_IN);
  for (int s = 0; s < 5; ++s) {
    const float4* p = (const float4*)(xrow + s * ATT_IN + lane * 8);
    float4 a = p[0], b = p[1];
    float xv[8] = {a.x, a.y, a.z, a.w, b.x, b.y, b.z, b.w};
    for (int h = 0; h < 4; ++h) {
      float acc = 0.f;
      for (int i = 0; i < 8; ++i) acc += xv[i] * wreg[h][i];
      part[s][h] = acc;
    }
  }
  for (int off = 32; off; off >>= 1)
    for (int s = 0; s < 5; ++s)
      for (int h = 0; h < 4; ++h)
        part[s][h] += __shfl_xor(part[s][h], off);
  if (lane < 20) {
    int h = lane / 5, s = lane % 5;
    float l[5];
    for (int s2 = 0; s2 < 5; ++s2) {
      float v = part[s2][h];
      l[s2] = v > 0.f ? v : 0.2f * v;   // leaky_relu(0.2)
    }
    float m = l[0];
    for (int s2 = 1; s2 < 5; ++s2) m = fmaxf(m, l[s2]);
    float sum = 0.f;
    for (int s2 = 0; s2 < 5; ++s2) sum += expf(l[s2] - m);
    att[(size_t)n * 20 + h * 5 + s] = expf(l[s] - m) / sum;
  }
}

// ---------------- pooled projection: xs0[n, h*128+p] = (sum_s att*x) @ W[h] ----------------
// BM=64 nodes, BN=128 (one head), BK=16, 256 threads
__global__ __launch_bounds__(256) void k_pooled(
    const float* __restrict__ x_spot, const float* __restrict__ W_att,
    const float* __restrict__ att, float* __restrict__ xs0) {
  __shared__ float As[16][68];
  __shared__ float Bs[16][132];
  int h = blockIdx.y;
  int mb = blockIdx.x * 64;
  int t = threadIdx.x;
  int ty = t >> 4, tx = t & 15;
  int ka = t & 15, ma0 = (t >> 4) * 4;
  int kb = t >> 5, nb0 = (t & 31) * 4;
  // hoist attention weights for my 4 A-rows
  float a5[4][5];
  for (int i = 0; i < 4; ++i) {
    int n = mb + ma0 + i;
    for (int s = 0; s < 5; ++s)
      a5[i][s] = (n < NN) ? att[(size_t)n * 20 + h * 5 + s] : 0.f;
  }
  const float* Wh = W_att + (size_t)h * ATT_IN * 128;
  float acc[4][8];
  for (int i = 0; i < 4; ++i)
    for (int j = 0; j < 8; ++j) acc[i][j] = 0.f;

  for (int k0 = 0; k0 < ATT_IN; k0 += 16) {
    for (int i = 0; i < 4; ++i) {
      int n = mb + ma0 + i;
      float v = 0.f;
      if (n < NN) {
        const float* xr = x_spot + (size_t)n * (5 * ATT_IN) + k0 + ka;
        v = a5[i][0] * xr[0] + a5[i][1] * xr[512] + a5[i][2] * xr[1024]
          + a5[i][3] * xr[1536] + a5[i][4] * xr[2048];
      }
      As[ka][ma0 + i] = v;
    }
    for (int kk = kb; kk < 16; kk += 8) {
      const float4 bv = *(const float4*)&Wh[(size_t)(k0 + kk) * 128 + nb0];
      *(float4*)&Bs[kk][nb0] = bv;
    }
    __syncthreads();
    for (int k = 0; k < 16; ++k) {
      float4 av = *(const float4*)&As[k][ty * 4];
      float4 b0 = *(const float4*)&Bs[k][tx * 8];
      float4 b1 = *(const float4*)&Bs[k][tx * 8 + 4];
      float a[4] = {av.x, av.y, av.z, av.w};
      float b[8] = {b0.x, b0.y, b0.z, b0.w, b1.x, b1.y, b1.z, b1.w};
      for (int i = 0; i < 4; ++i)
        for (int j = 0; j < 8; ++j) acc[i][j] += a[i] * b[j];
    }
    __syncthreads();
  }
  for (int i = 0; i < 4; ++i) {
    int n = mb + ty * 4 + i;
    if (n < NN) {
      float4 o0 = {acc[i][0], acc[i][1], acc[i][2], acc[i][3]};
      float4 o1 = {acc[i][4], acc[i][5], acc[i][6], acc[i][7]};
      float* dst = xs0 + (size_t)n * ATT_IN + h * 128 + tx * 8;
      *(float4*)dst = o0;
      *(float4*)(dst + 4) = o1;
    }
  }
}

// ---------------- generic f32 GEMM: C[M,N] = A[M,K] @ B[K,N] ----------------
// BM=128, BN=64, BK=16, 256 threads, 8x4 micro-tile
__global__ __launch_bounds__(256) void k_gemm(
    const float* __restrict__ A, const float* __restrict__ B,
    float* __restrict__ C, int M, int N, int K) {
  __shared__ float As[16][132];
  __shared__ float Bs[16][68];
  int mb = blockIdx.x * 128;
  int nb = blockIdx.y * 64;
  int t = threadIdx.x;
  int ty = t >> 4, tx = t & 15;
  int ka = t & 15, ma0 = (t >> 4) * 8;
  int kb = t >> 4, nb0 = (t & 15) * 4;
  float acc[8][4];
  for (int i = 0; i < 8; ++i)
    for (int j = 0; j < 4; ++j) acc[i][j] = 0.f;

  for (int k0 = 0; k0 < K; k0 += 16) {
    for (int i = 0; i < 8; ++i) {
      int m = mb + ma0 + i;
      As[ka][ma0 + i] = (m < M) ? A[(size_t)m * K + k0 + ka] : 0.f;
    }
    {
      const float4 bv = *(const float4*)&B[(size_t)(k0 + kb) * N + nb + nb0];
      *(float4*)&Bs[kb][nb0] = bv;
    }
    __syncthreads();
    for (int k = 0; k < 16; ++k) {
      float4 a0 = *(const float4*)&As[k][ty * 8];
      float4 a1 = *(const float4*)&As[k][ty * 8 + 4];
      float4 bv = *(const float4*)&Bs[k][tx * 4];
      float a[8] = {a0.x, a0.y, a0.z, a0.w, a1.x, a1.y, a1.z, a1.w};
      float b[4] = {bv.x, bv.y, bv.z, bv.w};
      for (int i = 0; i < 8; ++i)
        for (int j = 0; j < 4; ++j) acc[i][j] += a[i] * b[j];
    }
    __syncthreads();
  }
  for (int i = 0; i < 8; ++i) {
    int m = mb + ty * 8 + i;
    if (m < M) {
      float4 o = {acc[i][0], acc[i][1], acc[i][2], acc[i][3]};
      *(float4*)&C[(size_t)m * N + nb + tx * 4] = o;
    }
  }
}

// ---------------- CSR SpMM + relu + mean accumulate (+ output head) ----------------
// one wave per destination row; 64 lanes x float4 = 256 columns
// mode 0: mean = val;  mode 1: mean += val;  mode 2: mean = (mean+val)/3, head out
__global__ __launch_bounds__(256) void k_spmm(
    const int* __restrict__ rp, const int* __restrict__ col,
    const float* __restrict__ wv, const float* __restrict__ tin,
    float* __restrict__ xout, float* __restrict__ meanout,
    const float* __restrict__ Wout, const float* __restrict__ bout,
    float* __restrict__ headout, int mode) {
  int wave = threadIdx.x >> 6, lane = threadIdx.x & 63;
  int n = blockIdx.x * 4 + wave;
  if (n >= NN) return;
  int j0 = rp[n], j1 = rp[n + 1];
  float ax = 0.f, ay = 0.f, az = 0.f, aw = 0.f;
  for (int j = j0; j < j1; ++j) {
    int src = col[j];
    float w = wv[j];
    const float4 v = *(const float4*)&tin[(size_t)src * HID + lane * 4];
    ax += w * v.x; ay += w * v.y; az += w * v.z; aw += w * v.w;
  }
  float4 val = {fmaxf(ax, 0.f), fmaxf(ay, 0.f), fmaxf(az, 0.f), fmaxf(aw, 0.f)};
  *(float4*)&xout[(size_t)n * HID + lane * 4] = val;
  float4* mp = (float4*)&meanout[(size_t)n * HID + lane * 4];
  if (mode == 0) {
    *mp = val;
  } else {
    float4 pm = *mp;
    pm.x += val.x; pm.y += val.y; pm.z += val.z; pm.w += val.w;
    if (mode == 2) {
      const float third = 1.f / 3.f;
      pm.x *= third; pm.y *= third; pm.z *= third; pm.w *= third;
    }
    *mp = pm;
  }
  if (mode == 2) {
    const float4 w4 = *(const float4*)&Wout[lane * 4];
    float d = val.x * w4.x + val.y * w4.y + val.z * w4.z + val.w * w4.w;
    for (int off = 32; off; off >>= 1) d += __shfl_xor(d, off);
    if (lane == 0) headout[n] = d + bout[0];
  }
}

extern "C" void kernel_launch(void* const* d_in, const int* in_sizes, int n_in,
                              void* d_out, int out_size, void* d_ws, size_t ws_size,
                              hipStream_t stream) {
  const float* x_spot  = (const float*)d_in[0];
  const float* x_user  = (const float*)d_in[1];
  const int*   edge_us = (const int*)d_in[2];
  const int*   edge_su = (const int*)d_in[3];
  const float* W_att   = (const float*)d_in[4];
  const float* q_att   = (const float*)d_in[5];
  const float* W0_us   = (const float*)d_in[6];
  const float* W0_su   = (const float*)d_in[7];
  const float* Wmid_us = (const float*)d_in[8];
  const float* Wmid_su = (const float*)d_in[9];
  const float* W_out_s = (const float*)d_in[10];
  const float* b_out_s = (const float*)d_in[11];
  const float* W_out_u = (const float*)d_in[12];
  const float* b_out_u = (const float*)d_in[13];

  const int E = in_sizes[2] / 2;  // 600000

  float* out_mean_s = (float*)d_out;                       // [30000,256]
  float* out_mean_u = out_mean_s + (size_t)NN * HID;       // [30000,256]
  float* out_s      = out_mean_u + (size_t)NN * HID;       // [30000]
  float* out_u      = out_s + NN;                          // [30000]

  // ---- workspace layout (4-byte units) — total ~33.97M elems ≈ 136 MB ----
  // xs/xu ALIAS the xs0 region: xs0 is dead after the layer-0 t_s GEMM,
  // which precedes the first k_spmm write to xs (stream-ordered).
  int*   wsI = (int*)d_ws;
  float* wsF = (float*)d_ws;
  int* deg_us_s = wsI + 0;
  int* deg_us_d = wsI + 30000;
  int* deg_su_s = wsI + 60000;
  int* deg_su_d = wsI + 90000;
  int* fill_s   = wsI + 120000;
  int* fill_u   = wsI + 150000;
  int* rp_s     = wsI + 180000;      // 30001 (pad to 30016)
  int* rp_u     = wsI + 210016;
  int* col_s    = wsI + 240032;      // E
  int* col_u    = wsI + 840032;
  float* wv_s   = wsF + 1440032;     // E
  float* wv_u   = wsF + 2040032;
  float* wq     = wsF + 2640032;     // 2048
  float* att    = wsF + 2642080;     // 30000*20
  float* xs0    = wsF + 3242080;     // 30000*512 (61.4 MB)
  float* xs     = wsF + 3242080;     // alias: first half of xs0
  float* xu     = wsF + 10922080;    // alias: second half of xs0
  float* t_u    = wsF + 18602080;    // 30000*256
  float* t_s    = wsF + 26282080;    // 30000*256; end = 33,962,080 floats

  const int EB = (E + 255) / 256;

  // zero degree + fill counters (workspace is poisoned 0xAA before every call)
  hipMemsetAsync(d_ws, 0, 180000 * sizeof(int), stream);

  // graph preprocessing
  k_count_deg<<<EB, 256, 0, stream>>>(edge_us, edge_su, E,
                                      deg_us_s, deg_us_d, deg_su_s, deg_su_d);
  k_scan<<<1, 1024, 0, stream>>>(deg_us_d, rp_s, NN);
  k_scan<<<1, 1024, 0, stream>>>(deg_su_d, rp_u, NN);
  k_fill_csr<<<EB, 256, 0, stream>>>(edge_us, edge_us + E, deg_us_s, deg_us_d,
                                     rp_s, fill_s, col_s, wv_s, E);
  k_fill_csr<<<EB, 256, 0, stream>>>(edge_su, edge_su + E, deg_su_s, deg_su_d,
                                     rp_u, fill_u, col_u, wv_u, E);

  // attention front-end
  k_wq<<<8, 256, 0, stream>>>(W_att, q_att, wq);
  k_att<<<NN / 4, 256, 0, stream>>>(x_spot, wq, att);
  k_pooled<<<dim3((NN + 63) / 64, 4), 256, 0, stream>>>(x_spot, W_att, att, xs0);

  const int MB = (NN + 127) / 128;  // 235

  // layer 0 (K=512)
  k_gemm<<<dim3(MB, 4), 256, 0, stream>>>(x_user, W0_us, t_u, NN, HID, 512);
  k_gemm<<<dim3(MB, 4), 256, 0, stream>>>(xs0,    W0_su, t_s, NN, HID, 512);
  k_spmm<<<NN / 4, 256, 0, stream>>>(rp_s, col_s, wv_s, t_u, xs, out_mean_s,
                                     nullptr, nullptr, nullptr, 0);
  k_spmm<<<NN / 4, 256, 0, stream>>>(rp_u, col_u, wv_u, t_s, xu, out_mean_u,
                                     nullptr, nullptr, nullptr, 0);
  // layer 1 (K=256)
  k_gemm<<<dim3(MB, 4), 256, 0, stream>>>(xu, Wmid_us,           t_u, NN, HID, HID);
  k_gemm<<<dim3(MB, 4), 256, 0, stream>>>(xs, Wmid_su,           t_s, NN, HID, HID);
  k_spmm<<<NN / 4, 256, 0, stream>>>(rp_s, col_s, wv_s, t_u, xs, out_mean_s,
                                     nullptr, nullptr, nullptr, 1);
  k_spmm<<<NN / 4, 256, 0, stream>>>(rp_u, col_u, wv_u, t_s, xu, out_mean_u,
                                     nullptr, nullptr, nullptr, 1);
  // layer 2 (K=256) + heads + mean finalize
  k_gemm<<<dim3(MB, 4), 256, 0, stream>>>(xu, Wmid_us + 256 * 256, t_u, NN, HID, HID);
  k_gemm<<<dim3(MB, 4), 256, 0, stream>>>(xs, Wmid_su + 256 * 256, t_s, NN, HID, HID);
  k_spmm<<<NN / 4, 256, 0, stream>>>(rp_s, col_s, wv_s, t_u, xs, out_mean_s,
                                     W_out_s, b_out_s, out_s, 2);
  k_spmm<<<NN / 4, 256, 0, stream>>>(rp_u, col_u, wv_u, t_s, xu, out_mean_u,
                                     W_out_u, b_out_u, out_u, 2);
}